// Round 8
// baseline (435.546 us; speedup 1.0000x reference)
//
#include <hip/hip_runtime.h>

#define NB 8
#define SL 512
#define DM 1024
#define NH 16
#define DH 64

using bfrag = __attribute__((ext_vector_type(8))) short;   // 8 bf16 (4 VGPRs)
using facc  = __attribute__((ext_vector_type(4))) float;   // 4 fp32 acc

__device__ __forceinline__ float bf2f(ushort u) {
    return __uint_as_float(((unsigned)u) << 16);
}
__device__ __forceinline__ ushort f2bf(float f) {
    unsigned x = __float_as_uint(f);
    return (ushort)((x + 0x7FFFu + ((x >> 16) & 1u)) >> 16);   // RNE
}
__device__ __forceinline__ unsigned pack2(float a, float b) {
    return (unsigned)f2bf(a) | ((unsigned)f2bf(b) << 16);
}
__device__ __forceinline__ void gload16(const ushort* g, ushort* l) {
    __builtin_amdgcn_global_load_lds(
        (const __attribute__((address_space(1))) unsigned*)g,
        (__attribute__((address_space(3))) unsigned*)l, 16, 0, 0);
}

// ---------------------------------------------------------------------------
// Fused transpose-convert of ALL weights in one dispatch.
// z: 0=Wq 1=Wk 2=Wv 3=Wo 4=W1(3072x1024) 5=W2.  W[R,C] fp32 -> WT[C,R] bf16.
// grid (16, 48, 6); z!=4 uses only y<16.
// ---------------------------------------------------------------------------
__global__ __launch_bounds__(256)
void tconv_all(const float* __restrict__ Wq, const float* __restrict__ Wk,
               const float* __restrict__ Wv, const float* __restrict__ Wo,
               const float* __restrict__ W1, const float* __restrict__ W2,
               ushort* __restrict__ Wt)
{
    const int z = blockIdx.z;
    if (z != 4 && blockIdx.y >= 16) return;
    const float* W; ushort* WT; int R;
    const int D2 = DM * DM;
    switch (z) {
        case 0:  W = Wq; WT = Wt;          R = DM;     break;
        case 1:  W = Wk; WT = Wt + D2;     R = DM;     break;
        case 2:  W = Wv; WT = Wt + 2*D2;   R = DM;     break;
        case 3:  W = Wo; WT = Wt + 3*D2;   R = DM;     break;
        case 4:  W = W1; WT = Wt + 4*D2;   R = 3*DM;   break;
        default: W = W2; WT = Wt + 7*D2;   R = DM;     break;
    }
    __shared__ ushort T[64][68];
    const int tid = threadIdx.x;
    const int c0 = blockIdx.x * 64, r0 = blockIdx.y * 64;
    #pragma unroll
    for (int rr = 0; rr < 4; ++rr) {
        const int r = (tid >> 4) + rr * 16;
        const int c4 = (tid & 15) * 4;
        const float4 f = *(const float4*)(W + (size_t)(r0 + r) * DM + c0 + c4);
        T[c4+0][r] = f2bf(f.x); T[c4+1][r] = f2bf(f.y);
        T[c4+2][r] = f2bf(f.z); T[c4+3][r] = f2bf(f.w);
    }
    __syncthreads();
    #pragma unroll
    for (int rr = 0; rr < 4; ++rr) {
        const int c = (tid >> 4) + rr * 16;
        const int r4 = (tid & 15) * 4;
        *(ushort4*)(WT + (size_t)(c0 + c) * R + r0 + r4) =
            make_ushort4(T[c][r4+0], T[c][r4+1], T[c][r4+2], T[c][r4+3]);
    }
}

// ---------------------------------------------------------------------------
// bf16 MFMA GEMM: 128x128 tile, 4 waves, BK=64, double-buffered LDS staging.
//   out[m,n] = ACT( sum_k A[m,k]*B[k,n] + bias[n] ),  B given as BT[n,k].
// AFP32=0: A bf16 from A0 (rows >= Msplit from AM1, block-uniform).
// AFP32=1: A fp32, K-concat F0|F1|F2 (all stride DM), converted during
// staging; rows >= Msplit switch F0 -> FM1 (QKV text/image M-batching).
// XCD swizzle: clustN=0 m-clustered, 1 n-clustered. XOR chunk swizzle on
// LDS -> conflict-free ds_read_b128.
// OMODE 0: fp32 row-major. 2: bf16 row-major. 4: fused QKV epilogue --
// segment n>>10 selects Q-scatter(sigmoid) / K-scatter(sigmoid) /
// V-transpose(none) with per-segment bias.
// ---------------------------------------------------------------------------
template<int ACT, int OMODE, int AFP32>
__global__ __launch_bounds__(256, 2)
void mfma_gemm(const ushort* __restrict__ A0, const ushort* __restrict__ AM1,
               const float* __restrict__ F0, const float* __restrict__ F1,
               const float* __restrict__ F2, const float* __restrict__ FM1,
               const int KA1, const int KA2, const int Ktot, const int Msplit,
               const ushort* __restrict__ BT, const int ldb,
               const float* __restrict__ bias, const float* __restrict__ biasK,
               const float* __restrict__ biasV,
               float* __restrict__ outf, ushort* __restrict__ outb,
               ushort* __restrict__ outbK, ushort* __restrict__ outbVT,
               const int clustN)
{
    __shared__ ushort sh[32768];   // 2 buffers x (As 8192 + Bs 8192), 64 KB
    const int tid  = threadIdx.x;
    const int w    = tid >> 6;
    const int lane = tid & 63;
    const int ln   = lane & 15, qd = lane >> 4;
    const int wm = (w & 1) * 64, wn = (w >> 1) * 64;

    // ---- XCD-clustered block swizzle ----
    const int NTg = gridDim.x, MTg = gridDim.y;
    const int L   = blockIdx.x + NTg * blockIdx.y;
    const int xcd = L & 7, sIdx = L >> 3;
    int mt, nt;
    if (clustN) { const int np = NTg >> 3; nt = xcd * np + sIdx % np; mt = sIdx / np; }
    else        { mt = xcd * (MTg >> 3) + sIdx / NTg; nt = sIdx - (sIdx / NTg) * NTg; }
    const int m0 = mt * 128, n0 = nt * 128;

    // ---- M-concat source select (block-uniform) ----
    const ushort* A0u = A0;
    const float*  F0u = F0;
    int m0A = m0;
    if (Msplit && m0 >= Msplit) { A0u = AM1; F0u = FM1; m0A = m0 - Msplit; }

    const int arow = (lane >> 3);               // row-in-chunk 0..7
    const int kc8s = ((lane & 7) ^ arow) * 8;   // swizzled global k-chunk

    facc acc[4][4];
    #pragma unroll
    for (int i = 0; i < 4; ++i)
        #pragma unroll
        for (int j = 0; j < 4; ++j)
            acc[i][j] = (facc){0.f, 0.f, 0.f, 0.f};

    auto stage = [&](int k0, ushort* buf) {
        ushort* Asb = buf;
        ushort* Bsb = buf + 8192;
        #pragma unroll
        for (int t = 0; t < 4; ++t) {
            const int c = w * 4 + t;
            gload16(BT + (size_t)(n0 + c * 8 + arow) * ldb + k0 + kc8s,
                    &Bsb[c * 512]);
        }
        if (AFP32) {
            const float* src; int ko;
            if (k0 < KA1)      { src = F0u; ko = k0; }
            else if (k0 < KA2) { src = F1;  ko = k0 - KA1; }
            else               { src = F2;  ko = k0 - KA2; }
            #pragma unroll
            for (int t = 0; t < 4; ++t) {
                const int c = w * 4 + t;
                const float* s = src + (size_t)(m0A + c * 8 + arow) * DM + ko + kc8s;
                const float4 f0 = *(const float4*)s;
                const float4 f1 = *(const float4*)(s + 4);
                uint4 p;
                p.x = pack2(f0.x, f0.y); p.y = pack2(f0.z, f0.w);
                p.z = pack2(f1.x, f1.y); p.w = pack2(f1.z, f1.w);
                *(uint4*)&Asb[c * 512 + lane * 8] = p;
            }
        } else {
            #pragma unroll
            for (int t = 0; t < 4; ++t) {
                const int c = w * 4 + t;
                gload16(A0u + (size_t)(m0A + c * 8 + arow) * DM + k0 + kc8s,
                        &Asb[c * 512]);
            }
        }
    };

    stage(0, sh);
    for (int k0 = 0; k0 < Ktot; k0 += 64) {
        ushort* cur = sh + ((k0 >> 6) & 1) * 16384;
        ushort* nxt = sh + (((k0 >> 6) & 1) ^ 1) * 16384;
        __syncthreads();                       // drains stage(k0)
        if (k0 + 64 < Ktot) stage(k0 + 64, nxt);   // overlaps compute below
        ushort* Asb = cur;
        ushort* Bsb = cur + 8192;
        #pragma unroll
        for (int ks = 0; ks < 2; ++ks) {
            const int ch = (ks * 4 + qd) ^ (ln & 7);   // swizzled chunk
            bfrag af[4], bfv[4];
            #pragma unroll
            for (int i = 0; i < 4; ++i)
                af[i] = *(const bfrag*)&Asb[(wm + i*16 + ln) * 64 + ch * 8];
            #pragma unroll
            for (int j = 0; j < 4; ++j)
                bfv[j] = *(const bfrag*)&Bsb[(wn + j*16 + ln) * 64 + ch * 8];
            #pragma unroll
            for (int i = 0; i < 4; ++i)
                #pragma unroll
                for (int j = 0; j < 4; ++j)
                    acc[i][j] = __builtin_amdgcn_mfma_f32_16x16x32_bf16(
                        af[i], bfv[j], acc[i][j], 0, 0, 0);
        }
    }

    if (OMODE == 4) {
        const int seg   = n0 >> 10;        // 0=Q 1=K 2=V (block-uniform)
        const int nloc0 = n0 & 1023;
        const float* bs = (seg == 0) ? bias : (seg == 1) ? biasK : biasV;
        if (seg < 2) {
            ushort* ob = (seg == 0) ? outb : outbK;
            #pragma unroll
            for (int j = 0; j < 4; ++j) {
                const int nl = nloc0 + wn + j * 16 + ln;
                const float bn = bs[nl];
                #pragma unroll
                for (int i = 0; i < 4; ++i) {
                    const int mb = m0 + wm + i * 16 + qd * 4;
                    #pragma unroll
                    for (int r = 0; r < 4; ++r) {
                        const float v = 1.f / (1.f + __expf(-(acc[i][j][r] + bn)));
                        const int m = mb + r;
                        const int g = m >> 9, l = m & 511;
                        ob[(((size_t)(g * NH + (nl >> 6))) * SL + l) * DH + (nl & 63)]
                            = f2bf(v);
                    }
                }
            }
        } else {
            // V: in-LDS swizzled transpose -> [g,h,d,l] coalesced stores
            __syncthreads();
            #pragma unroll
            for (int j = 0; j < 4; ++j) {
                const int n_l = wn + j * 16 + ln;
                const float bn = bs[nloc0 + n_l];
                #pragma unroll
                for (int i = 0; i < 4; ++i) {
                    #pragma unroll
                    for (int r = 0; r < 4; ++r) {
                        const int m_l = wm + i * 16 + qd * 4 + r;
                        const int c = (m_l >> 3) ^ (n_l & 7);
                        sh[n_l * 128 + c * 8 + (m_l & 7)] = f2bf(acc[i][j][r] + bn);
                    }
                }
            }
            __syncthreads();
            const int n_l = tid >> 1, half = tid & 1;
            const int nl = nloc0 + n_l;
            const int g = m0 >> 9, l0 = m0 & 511;
            ushort* dst = outbVT +
                (((size_t)(g * NH + (nl >> 6))) * DH + (nl & 63)) * SL + l0;
            #pragma unroll
            for (int u = 0; u < 8; ++u) {
                const int c = half * 8 + u;
                const int cs = c ^ (n_l & 7);
                *(uint4*)(dst + c * 8) = *(const uint4*)&sh[n_l * 128 + cs * 8];
            }
        }
        return;
    }

    // ---- standard epilogue: C/D layout col=lane&15, row=qd*4+r ----
    #pragma unroll
    for (int j = 0; j < 4; ++j) {
        const int n = n0 + wn + j * 16 + ln;
        const float bn = bias[n];
        #pragma unroll
        for (int i = 0; i < 4; ++i) {
            const int mb = m0 + wm + i * 16 + qd * 4;
            #pragma unroll
            for (int r = 0; r < 4; ++r) {
                float v = acc[i][j][r] + bn;
                if (ACT == 1)      v = 1.f / (1.f + __expf(-v));
                else if (ACT == 2) v = v > 0.f ? v : 0.f;
                const int m = mb + r;
                if (OMODE == 0) outf[(size_t)m * DM + n] = v;
                else            outb[(size_t)m * DM + n] = f2bf(v);
            }
        }
    }
}

// ---------------------------------------------------------------------------
// MFMA fuzzy attention. One (b,h,128-q-tile) per block, 4 waves (2x2).
// Q [g,h,l,d] / K [g,h,l,d] / VT [g,h,d,l], all bf16. Scores in [0,1] ->
// exp without max subtraction. E round-trips LDS (XOR-swizzled) to convert
// MFMA C-layout -> A-layout for PV. XOR chunk swizzle on K/VT staging.
// LDS = 16K (K) + 16K (VT) + 32K (E) = 64 KB -> 2 blocks/CU.
// ---------------------------------------------------------------------------
__global__ __launch_bounds__(256, 2)
void attn2_k(const ushort* __restrict__ Qm, const ushort* __restrict__ Km,
             const ushort* __restrict__ VTm, ushort* __restrict__ AO,
             float* __restrict__ RS)
{
    __shared__ ushort Ks[128 * 64];
    __shared__ ushort VTs[64 * 128];
    __shared__ ushort Es[128 * 128];
    const int tid  = threadIdx.x;
    const int w    = tid >> 6;
    const int lane = tid & 63;
    const int ln   = lane & 15, qd = lane >> 4;
    const int wm  = (w & 1) * 64;
    const int wns = (w >> 1) * 64;
    const int wnd = (w >> 1) * 32;
    const int qt = blockIdx.x, h = blockIdx.y, b = blockIdx.z;
    const size_t ho = ((size_t)(b * NH + h)) * SL * DH;
    const ushort* Qg  = Qm  + ho + (size_t)qt * 128 * DH;
    const ushort* Kg  = Km  + ho;
    const ushort* VTg = VTm + ho;

    bfrag qf[4][2];
    #pragma unroll
    for (int i = 0; i < 4; ++i)
        #pragma unroll
        for (int ks = 0; ks < 2; ++ks)
            qf[i][ks] = *(const bfrag*)(Qg + (size_t)(wm + i*16 + ln) * DH + ks*32 + qd*8);

    facc oacc[4][2];
    #pragma unroll
    for (int i = 0; i < 4; ++i)
        #pragma unroll
        for (int j = 0; j < 2; ++j)
            oacc[i][j] = (facc){0.f, 0.f, 0.f, 0.f};
    float rp[4][4];
    #pragma unroll
    for (int i = 0; i < 4; ++i)
        #pragma unroll
        for (int r = 0; r < 4; ++r)
            rp[i][r] = 0.f;

    const int arow = lane >> 3;
    const int kc8s = ((lane & 7) ^ arow) * 8;
    const int vrow = lane >> 4;

    for (int kc = 0; kc < 4; ++kc) {
        __syncthreads();
        #pragma unroll
        for (int t = 0; t < 4; ++t) {
            const int c = w * 4 + t;
            const int vc8s = ((lane & 15) ^ ((c * 4 + vrow) & 7)) * 8;
            gload16(Kg + (size_t)(kc*128 + c*8 + arow) * DH + kc8s, &Ks[c * 512]);
            gload16(VTg + (size_t)(c*4 + vrow) * SL + kc*128 + vc8s, &VTs[c * 512]);
        }
        __syncthreads();

        facc sacc[4][4];
        #pragma unroll
        for (int i = 0; i < 4; ++i)
            #pragma unroll
            for (int j = 0; j < 4; ++j)
                sacc[i][j] = (facc){0.f, 0.f, 0.f, 0.f};
        #pragma unroll
        for (int ks = 0; ks < 2; ++ks) {
            const int ch = (ks * 4 + qd) ^ (ln & 7);
            bfrag kf[4];
            #pragma unroll
            for (int j = 0; j < 4; ++j)
                kf[j] = *(const bfrag*)&Ks[(wns + j*16 + ln) * 64 + ch * 8];
            #pragma unroll
            for (int i = 0; i < 4; ++i)
                #pragma unroll
                for (int j = 0; j < 4; ++j)
                    sacc[i][j] = __builtin_amdgcn_mfma_f32_16x16x32_bf16(
                        qf[i][ks], kf[j], sacc[i][j], 0, 0, 0);
        }

        #pragma unroll
        for (int i = 0; i < 4; ++i) {
            #pragma unroll
            for (int r = 0; r < 4; ++r) {
                const int q = wm + i*16 + qd*4 + r;
                float p = 0.f;
                #pragma unroll
                for (int j = 0; j < 4; ++j) {
                    const float e = __expf(sacc[i][j][r] * 0.015625f);
                    const int key = wns + j*16 + ln;
                    const int c = (key >> 3) ^ (q & 7);
                    Es[q * 128 + c * 8 + (key & 7)] = f2bf(e);
                    p += e;
                }
                p += __shfl_xor(p, 1, 16);
                p += __shfl_xor(p, 2, 16);
                p += __shfl_xor(p, 4, 16);
                p += __shfl_xor(p, 8, 16);
                rp[i][r] += p;
            }
        }
        __syncthreads();

        #pragma unroll
        for (int ks2 = 0; ks2 < 4; ++ks2) {
            const int vch = (ks2 * 4 + qd) ^ (ln & 7);
            bfrag ea[4], vb[2];
            #pragma unroll
            for (int i = 0; i < 4; ++i) {
                const int q = wm + i*16 + ln;
                const int cs = (ks2*4 + qd) ^ (q & 7);
                ea[i] = *(const bfrag*)&Es[q * 128 + cs * 8];
            }
            #pragma unroll
            for (int j = 0; j < 2; ++j)
                vb[j] = *(const bfrag*)&VTs[(wnd + j*16 + ln) * 128 + vch * 8];
            #pragma unroll
            for (int i = 0; i < 4; ++i)
                #pragma unroll
                for (int j = 0; j < 2; ++j)
                    oacc[i][j] = __builtin_amdgcn_mfma_f32_16x16x32_bf16(
                        ea[i], vb[j], oacc[i][j], 0, 0, 0);
        }
    }

    __syncthreads();
    float* rsls = (float*)Ks;
    if (ln == 0) {
        #pragma unroll
        for (int i = 0; i < 4; ++i)
            #pragma unroll
            for (int r = 0; r < 4; ++r)
                rsls[(w >> 1) * 128 + wm + i*16 + qd*4 + r] = rp[i][r];
    }
    __syncthreads();
    if (tid < 128) {
        const float t = rsls[tid] + rsls[128 + tid];
        RS[(size_t)(b * NH + h) * SL + qt * 128 + tid] = t;
        rsls[tid] = t;
    }
    __syncthreads();

    #pragma unroll
    for (int i = 0; i < 4; ++i) {
        #pragma unroll
        for (int r = 0; r < 4; ++r) {
            const int q = wm + i*16 + qd*4 + r;
            const float inv = 1.f / rsls[q];
            const size_t rowo = ((size_t)(b*SL + qt*128 + q)) * DM + h*DH;
            #pragma unroll
            for (int j = 0; j < 2; ++j)
                AO[rowo + wnd + j*16 + ln] = f2bf(oacc[i][j][r] * inv);
        }
    }
}

// ---------------------------------------------------------------------------
// avg_attn via MFMA: one 64x64 avga tile per block (grid 8x8x8), 16-head
// loop. Q/K staged raw bf16 via global_load_lds; scores on the matrix pipe;
// exp + head-accumulate on VALU.
// ---------------------------------------------------------------------------
__global__ __launch_bounds__(256, 2)
void avg3_k(const ushort* __restrict__ Qm, const ushort* __restrict__ Km,
            const float* __restrict__ RS, float* __restrict__ avga)
{
    __shared__ ushort Qs[64 * 64];
    __shared__ ushort Kt[64 * 64];
    __shared__ float rss[64];
    const int tid  = threadIdx.x;
    const int w    = tid >> 6;
    const int lane = tid & 63;
    const int ln   = lane & 15, qd = lane >> 4;
    const int wq = (w & 1) * 32, wk = (w >> 1) * 32;
    const int kt = blockIdx.x, qt = blockIdx.y, b = blockIdx.z;

    const int arow = lane >> 3;
    const int kc8s = ((lane & 7) ^ arow) * 8;

    float acc[2][2][4];
    #pragma unroll
    for (int i = 0; i < 2; ++i)
        #pragma unroll
        for (int j = 0; j < 2; ++j)
            #pragma unroll
            for (int r = 0; r < 4; ++r)
                acc[i][j][r] = 0.f;

    for (int h = 0; h < NH; ++h) {
        const size_t ho = ((size_t)(b * NH + h)) * SL * DH;
        __syncthreads();
        #pragma unroll
        for (int t = 0; t < 2; ++t) {
            const int c = w * 2 + t;
            gload16(Qm + ho + (size_t)(qt*64 + c*8 + arow) * DH + kc8s, &Qs[c * 512]);
            gload16(Km + ho + (size_t)(kt*64 + c*8 + arow) * DH + kc8s, &Kt[c * 512]);
        }
        if (tid < 64) rss[tid] = RS[(size_t)(b*NH + h)*SL + qt*64 + tid];
        __syncthreads();

        facc s[2][2];
        #pragma unroll
        for (int i = 0; i < 2; ++i)
            #pragma unroll
            for (int j = 0; j < 2; ++j)
                s[i][j] = (facc){0.f, 0.f, 0.f, 0.f};
        #pragma unroll
        for (int ks = 0; ks < 2; ++ks) {
            const int ch = (ks * 4 + qd) ^ (ln & 7);
            bfrag qa[2], kb[2];
            #pragma unroll
            for (int i = 0; i < 2; ++i)
                qa[i] = *(const bfrag*)&Qs[(wq + i*16 + ln) * 64 + ch * 8];
            #pragma unroll
            for (int j = 0; j < 2; ++j)
                kb[j] = *(const bfrag*)&Kt[(wk + j*16 + ln) * 64 + ch * 8];
            #pragma unroll
            for (int i = 0; i < 2; ++i)
                #pragma unroll
                for (int j = 0; j < 2; ++j)
                    s[i][j] = __builtin_amdgcn_mfma_f32_16x16x32_bf16(
                        qa[i], kb[j], s[i][j], 0, 0, 0);
        }
        #pragma unroll
        for (int i = 0; i < 2; ++i) {
            #pragma unroll
            for (int r = 0; r < 4; ++r) {
                const float ir = 0.0625f / rss[wq + i*16 + qd*4 + r];
                #pragma unroll
                for (int j = 0; j < 2; ++j)
                    acc[i][j][r] += __expf(s[i][j][r] * 0.015625f) * ir;
            }
        }
    }
    #pragma unroll
    for (int i = 0; i < 2; ++i) {
        #pragma unroll
        for (int r = 0; r < 4; ++r) {
            const int q = wq + i*16 + qd*4 + r;
            #pragma unroll
            for (int j = 0; j < 2; ++j)
                avga[((size_t)(b*SL + qt*64 + q)) * SL + kt*64 + wk + j*16 + ln]
                    = acc[i][j][r];
        }
    }
}

// ---------------------------------------------------------------------------
extern "C" void kernel_launch(void* const* d_in, const int* in_sizes, int n_in,
                              void* d_out, int out_size, void* d_ws, size_t ws_size,
                              hipStream_t stream)
{
    (void)in_sizes; (void)n_in; (void)out_size; (void)ws_size;
    const float* text  = (const float*)d_in[0];
    const float* image = (const float*)d_in[1];
    const float* Wq = (const float*)d_in[2];
    const float* bq = (const float*)d_in[3];
    const float* Wk = (const float*)d_in[4];
    const float* bk = (const float*)d_in[5];
    const float* Wv = (const float*)d_in[6];
    const float* bv = (const float*)d_in[7];
    const float* Wo = (const float*)d_in[8];
    const float* bo = (const float*)d_in[9];
    const float* W1 = (const float*)d_in[10];
    const float* b1 = (const float*)d_in[11];
    const float* W2 = (const float*)d_in[12];
    const float* b2 = (const float*)d_in[13];
    float* out = (float*)d_out;

    const size_t SZ   = (size_t)NB * SL * DM;   // 4,194,304
    const size_t HALF = SZ;
    const size_t D2   = (size_t)DM * DM;

    // ---- workspace layout (bf16 = ushort), ~75.8 MB ----
    ushort* Qb  = (ushort*)d_ws;        // [16,NH,SL,DH]
    ushort* Kb  = Qb  + 2*SZ;           // [16,NH,SL,DH]
    ushort* VT  = Kb  + 2*SZ;           // [16,NH,DH,SL]
    ushort* AOt = VT  + 2*SZ;           // [4096,1024]
    ushort* Wt  = AOt + SZ;             // transposed weights arena, 8*DM^2
    float*  RS  = (float*)(Wt + 8*D2);  // [8,NH,SL]
    ushort* AOi    = VT + HALF;         // reuses VT-image (dead after attn dir-1)
    ushort* hidden = Qb;                // reuses Q-text (dead after avg3)

    float* text_cross = out;            // fused out-proj writes rows 0..8191
    float* comp       = out + 2*SZ;
    float* avga       = out + 3*SZ;

    const dim3 blk(256);

    // ---- all weight transposes in one dispatch ----
    tconv_all<<<dim3(16, 48, 6), blk, 0, stream>>>(Wq, Wk, Wv, Wo, W1, W2, Wt);

    // ---- fused Q/K/V projection: M=8192 (text|image fp32), N=3072 ----
    mfma_gemm<0,4,1><<<dim3(24,64), blk, 0, stream>>>(
        nullptr, nullptr, text, nullptr, nullptr, image,
        DM, DM, DM, 4096, Wt, DM, bq, bk, bv, nullptr, Qb, Kb, VT, 1);

    // ---- attention dir-1 (Q text, K/V image), avg_attn, dir-2 ----
    attn2_k<<<dim3(SL/128, NH, NB), blk, 0, stream>>>(Qb, Kb + HALF, VT + HALF, AOt, RS);
    avg3_k<<<dim3(SL/64, SL/64, NB), blk, 0, stream>>>(Qb, Kb + HALF, RS, avga);
    attn2_k<<<dim3(SL/128, NH, NB), blk, 0, stream>>>(Qb + HALF, Kb, VT, AOi, RS);

    // ---- fused output projections: M=8192 (AOt rows 0.., AOi rows 4096..) ----
    mfma_gemm<0,0,0><<<dim3(8,64), blk, 0, stream>>>(
        AOt, AOi, nullptr, nullptr, nullptr, nullptr,
        DM, DM, DM, 4096, Wt + 3*D2, DM, bo, nullptr, nullptr,
        text_cross, nullptr, nullptr, nullptr, 0);

    // ---- MLP: concat(text, image, text_cross) fp32 @ W1 -> relu -> @ W2 ----
    mfma_gemm<2,2,1><<<dim3(8,32), blk, 0, stream>>>(
        nullptr, nullptr, text, image, text_cross, nullptr,
        DM, 2*DM, 3*DM, 0, Wt + 4*D2, 3*DM, b1, nullptr, nullptr,
        nullptr, hidden, nullptr, nullptr, 0);
    mfma_gemm<0,0,0><<<dim3(8,32), blk, 0, stream>>>(
        hidden, nullptr, nullptr, nullptr, nullptr, nullptr,
        DM, DM, DM, 0, Wt + 7*D2, DM, b2, nullptr, nullptr,
        comp, nullptr, nullptr, nullptr, 0);
}